// Round 12
// baseline (181.101 us; speedup 1.0000x reference)
//
#include <hip/hip_runtime.h>

typedef float    f32x4 __attribute__((ext_vector_type(4)));
typedef _Float16 f16x2 __attribute__((ext_vector_type(2)));
typedef _Float16 f16x4 __attribute__((ext_vector_type(4)));
typedef _Float16 f16x8 __attribute__((ext_vector_type(8)));
typedef int      i32x4 __attribute__((ext_vector_type(4)));

namespace {
constexpr int B_ = 2, L_ = 2048, S_ = 2048, H_ = 16, E_ = 64;
constexpr int MBLK = 128;        // q rows per block (4 waves x 32)
constexpr int NT = 64;           // s-tile width
constexpr int NTILES = S_ / NT;  // 32

#define SCALE2f 0.1803368801111204f /* 0.125 * log2(e) */
#define MBIAS2f -1.8033688e8f       /* -1e9 * 0.125 * log2(e): exp2 -> exactly 0 */

// ws layout: [0,1MiB) mask bits | Kh f16 [b,h,s,e] | Vh f16 [b,h,e,s]
constexpr size_t KHOFF = (size_t)1 << 20;
constexpr size_t VHOFF = KHOFF + (size_t)B_ * H_ * S_ * E_ * 2;

__device__ __forceinline__ f16x2 cvt2(float a, float b) {
  return __builtin_bit_cast(f16x2, __builtin_amdgcn_cvt_pkrtz(a, b));
}
__device__ __forceinline__ int pkh(float a, float b) {
  return __builtin_bit_cast(int, __builtin_amdgcn_cvt_pkrtz(a, b));
}
union H8 { f16x8 v; i32x4 i; };
union H4 { f16x4 v; f16x2 h[2]; };

#define GLOAD_LDS16(g, l)                                              \
  __builtin_amdgcn_global_load_lds(                                    \
      (const __attribute__((address_space(1))) void*)(g),              \
      (__attribute__((address_space(3))) void*)(l), 16, 0, 0)
}  // namespace

// ---- fused pre-pass: maskpack (1024 blks) | kcvt (2048 blks) | vcvt (1024 blks)
extern "C" __global__ __launch_bounds__(256)
void prep_kernel(const float* __restrict__ Mg, const float* __restrict__ Kg,
                 const float* __restrict__ Vg, unsigned long long* __restrict__ Wb,
                 _Float16* __restrict__ Kh, _Float16* __restrict__ Vh) {
  __shared__ _Float16 T[64][72];
  const int bid = blockIdx.x;
  const int tid = threadIdx.x;
  if (bid < 1024) {
    // mask fp32 -> 1 bit/elem, u64 per (row, 64-s-chunk)
    const int w    = (bid * 256 + tid) >> 6;
    const int lane = tid & 63;
    const float* src = Mg + (size_t)w * 2048 + lane;
    unsigned long long* dst = Wb + (size_t)w * 32;
#pragma unroll 8
    for (int j = 0; j < 32; ++j) {
      const unsigned long long bits = __ballot(src[j * 64] > 0.5f);
      if (lane == 0) dst[j] = bits;
    }
  } else if (bid < 3072) {
    // K [b,s,h,e] f32 -> Kh [b,h,s,e] f16
    const int idx = (bid - 1024) * 256 + tid;  // 8-e chunk id
    const int j = idx & 7;
    const int h = (idx >> 3) & (H_ - 1);
    const int s = (idx >> 7) & (S_ - 1);
    const int b = idx >> 18;
    const float* src = Kg + ((((size_t)b * S_ + s) * H_ + h) << 6) + j * 8;
    f32x4 x = *(const f32x4*)src, y = *(const f32x4*)(src + 4);
    i32x4 w = {pkh(x[0], x[1]), pkh(x[2], x[3]), pkh(y[0], y[1]), pkh(y[2], y[3])};
    *(i32x4*)(Kh + ((((size_t)b * H_ + h) * S_ + s) << 6) + j * 8) = w;
  } else {
    // V [b,s,h,e] f32 -> Vh [b,h,e,s] f16 (transpose via LDS)
    const int vb = bid - 3072;
    const int st = vb & 31;
    const int h  = (vb >> 5) & (H_ - 1);
    const int b  = vb >> 9;
    const int sl = tid >> 2;
    const int e0 = (tid & 3) << 4;
    const float* src = Vg + ((((size_t)b * S_ + st * 64 + sl) * H_ + h) << 6) + e0;
#pragma unroll
    for (int i = 0; i < 4; ++i) {
      f32x4 x = *(const f32x4*)(src + i * 4);
#pragma unroll
      for (int c = 0; c < 4; ++c) T[e0 + i * 4 + c][sl] = (_Float16)x[c];
    }
    __syncthreads();
    const int er = tid >> 2;
    const int s0 = (tid & 3) << 4;
    _Float16* dst = Vh + (((((size_t)b * H_ + h) << 6) + er) * S_) + st * 64 + s0;
    *(i32x4*)dst       = *(const i32x4*)&T[er][s0];
    *(i32x4*)(dst + 8) = *(const i32x4*)&T[er][s0 + 8];
  }
}

extern "C" __global__ __launch_bounds__(256, 2)
void fattn_kernel(const float* __restrict__ Qg, const _Float16* __restrict__ Kh,
                  const _Float16* __restrict__ Vh, const unsigned long long* __restrict__ Wb,
                  float* __restrict__ Og) {
  // unpadded (DMA dest lane-contiguous); bank safety via XOR-granule swizzle
  __shared__ __align__(16) _Float16 Ks[2][NT][64];  // 16 KB
  __shared__ __align__(16) _Float16 Vt[3][E_][64];  // 24 KB (triple: PV lags one tile)

  const int tid  = threadIdx.x;
  const int wv   = tid >> 6;
  const int lane = tid & 63;
  const int qd   = lane >> 4;
  const int cl   = lane & 15;
  const int sw   = cl & 7;  // reader swizzle key (row & 7)

  // XCD-locality: bid%8 == bh%8 -> all 16 q-blocks of one (b,h) on one XCD
  const int bid = blockIdx.x;
  const int qb  = bid >> 5;
  const int bh  = bid & 31;
  const int h   = bh & (H_ - 1);
  const int b   = bh >> 4;

  const int l0 = qb * MBLK + wv * 32;

  // ---- Q fragments (B-operand of S^T = K Q^T), f16, from f32 global
  f16x8 qf[2][2];
#pragma unroll
  for (int mt = 0; mt < 2; ++mt) {
    const float* qp = Qg + ((((size_t)b * L_ + (l0 + mt * 16 + cl)) * H_ + h) << 6);
#pragma unroll
    for (int kb = 0; kb < 2; ++kb) {
      const int e0 = qd * 8 + kb * 32;
      f32x4 x = *(const f32x4*)(qp + e0);
      f32x4 y = *(const f32x4*)(qp + e0 + 4);
      H8 u;
      u.i = (i32x4){pkh(x[0], x[1]), pkh(x[2], x[3]), pkh(y[0], y[1]), pkh(y[2], y[3])};
      qf[mt][kb] = u.v;
    }
  }

  // ---- DMA lane constants: lane = 8*row_local + granule_slot
  const int rl  = lane >> 3;
  const int gsl = lane & 7;
  const int gsw = gsl ^ rl;  // swizzled source granule
  const _Float16* khb = Kh + ((((size_t)b * H_ + h) * S_) << 6);          // [s][e]
  const _Float16* vhb = Vh + ((((size_t)b * H_ + h) << 6) * (size_t)S_);  // [e][s]

  const unsigned long long* wbp = Wb + (((size_t)b * L_ + (l0 + cl)) << 5);

  auto dma = [&](int kbuf, int vbuf, int t) {
#pragma unroll
    for (int p = 0; p < 2; ++p) {
      const int r0 = p * 32 + wv * 8;
      const _Float16* ksrc = khb + (((size_t)(t * 64 + r0 + rl)) << 6) + gsw * 8;
      GLOAD_LDS16(ksrc, &Ks[kbuf][r0][0]);
      const _Float16* vsrc = vhb + (size_t)(r0 + rl) * S_ + t * 64 + gsw * 8;
      GLOAD_LDS16(vsrc, &Vt[vbuf][r0][0]);
    }
  };

  const f32x4 zero4 = {0.f, 0.f, 0.f, 0.f};
  f32x4 acc[2][4];
#pragma unroll
  for (int mt = 0; mt < 2; ++mt)
#pragma unroll
    for (int et = 0; et < 4; ++et) acc[mt][et] = zero4;
  f32x4 rs4[2] = {zero4, zero4};

  auto qk = [&](int kbuf, f32x4 sc[4][2]) {
#pragma unroll
    for (int nt = 0; nt < 4; ++nt) {
      const _Float16* krow = &Ks[kbuf][nt * 16 + cl][0];
      const f16x8 a0 = *(const f16x8*)(krow + ((qd ^ sw) << 3));
      const f16x8 a1 = *(const f16x8*)(krow + (((qd + 4) ^ sw) << 3));
#pragma unroll
      for (int mt = 0; mt < 2; ++mt) {
        f32x4 c = zero4;
        c = __builtin_amdgcn_mfma_f32_16x16x32_f16(a0, qf[mt][0], c, 0, 0, 0);
        c = __builtin_amdgcn_mfma_f32_16x16x32_f16(a1, qf[mt][1], c, 0, 0, 0);
        sc[nt][mt] = c;  // q = mt*16+cl, s = nt*16 + qd*4 + r
      }
    }
  };

  auto softmax = [&](unsigned long long w, f32x4 sc[4][2], f16x4 pa[2][4]) {
    if (w == ~0ull) {  // all-attend fast path
#pragma unroll
      for (int mt = 0; mt < 2; ++mt)
#pragma unroll
        for (int nt = 0; nt < 4; ++nt) {
          f32x4 p;
#pragma unroll
          for (int r = 0; r < 4; ++r)
            p[r] = __builtin_amdgcn_exp2f(sc[nt][mt][r] * SCALE2f);
          rs4[mt] += p;
          H4 u;
          u.h[0] = cvt2(p[0], p[1]);
          u.h[1] = cvt2(p[2], p[3]);
          pa[mt][nt] = u.v;
        }
    } else {
      const unsigned lo = (unsigned)w;
      const unsigned hi = (unsigned)(w >> 32);
#pragma unroll
      for (int mt = 0; mt < 2; ++mt)
#pragma unroll
        for (int nt = 0; nt < 4; ++nt) {
          const unsigned shm = ((nt < 2) ? lo : hi) >> ((nt & 1) * 16 + qd * 4);
          f32x4 p;
#pragma unroll
          for (int r = 0; r < 4; ++r) {
            const float bias = (shm & (1u << r)) ? 0.f : MBIAS2f;
            p[r] = __builtin_amdgcn_exp2f(__builtin_fmaf(sc[nt][mt][r], SCALE2f, bias));
          }
          rs4[mt] += p;
          H4 u;
          u.h[0] = cvt2(p[0], p[1]);
          u.h[1] = cvt2(p[2], p[3]);
          pa[mt][nt] = u.v;
        }
    }
  };

  auto pv = [&](int vbuf, f16x4 pa[2][4]) {
#pragma unroll
    for (int nt = 0; nt < 4; ++nt)
#pragma unroll
      for (int et = 0; et < 4; ++et) {
        const _Float16* vrow = &Vt[vbuf][et * 16 + cl][0];
        const f16x4 bv = *(const f16x4*)(vrow + ((((2 * nt + (qd >> 1)) ^ sw) << 3) + ((qd & 1) << 2)));
        acc[0][et] = __builtin_amdgcn_mfma_f32_16x16x16f16(pa[0][nt], bv, acc[0][et], 0, 0, 0);
        acc[1][et] = __builtin_amdgcn_mfma_f32_16x16x16f16(pa[1][nt], bv, acc[1][et], 0, 0, 0);
      }
  };

  // ---- prologue: tile 0 staged, QK(0)+softmax(0); PV lags one tile
  f16x4 pa[2][4];
  dma(0, 0, 0);
  unsigned long long mwcur = wbp[0];
  __syncthreads();
  dma(1, 1, 1);
  {
    f32x4 sc[4][2];
    qk(0, sc);
    softmax(mwcur, sc, pa);
  }
  mwcur = wbp[1];

  int vr = 0;  // Vt index of tile t-1 entering body t
  int vw = 2;  // Vt index of tile t+1 entering body t
  for (int t = 1; t < NTILES; ++t) {
    __syncthreads();  // drains DMA(t); all waves done with QK(t-1), PV(t-2)
    if (t + 1 < NTILES) dma((t + 1) & 1, vw, t + 1);
    const unsigned long long mwnext = (t + 1 < NTILES) ? wbp[t + 1] : 0;

    f32x4 sc[4][2];
    qk(t & 1, sc);     // QK(t)   — independent of pa
    pv(vr, pa);        // PV(t-1) — independent of sc; overlaps QK/softmax pipes
    softmax(mwcur, sc, pa);  // softmax(t) -> pa

    mwcur = mwnext;
    vr = (vr == 2) ? 0 : vr + 1;
    vw = (vw == 2) ? 0 : vw + 1;
  }
  pv(vr, pa);  // PV(NTILES-1); its DMA drained at the last barrier

  // ---- epilogue: row-sum reduce, broadcast inv per q-row, store
#pragma unroll
  for (int mt = 0; mt < 2; ++mt) {
    float v = rs4[mt][0] + rs4[mt][1] + rs4[mt][2] + rs4[mt][3];
    v += __shfl_xor(v, 16, 64);
    v += __shfl_xor(v, 32, 64);  // every lane: sum for q = mt*16 + cl
#pragma unroll
    for (int r = 0; r < 4; ++r) {
      const float invq = 1.0f / __shfl(v, qd * 4 + r, 64);
      const int l = l0 + mt * 16 + qd * 4 + r;
      float* op = Og + ((((size_t)b * H_ + h) * L_ + l) << 6) + cl;
#pragma unroll
      for (int et = 0; et < 4; ++et) op[et * 16] = acc[mt][et][r] * invq;
    }
  }
}

extern "C" void kernel_launch(void* const* d_in, const int* in_sizes, int n_in,
                              void* d_out, int out_size, void* d_ws, size_t ws_size,
                              hipStream_t stream) {
  const float* Q = (const float*)d_in[0];
  const float* K = (const float*)d_in[1];
  const float* V = (const float*)d_in[2];
  const float* M = (const float*)d_in[3];
  float* O = (float*)d_out;
  unsigned long long* Wb = (unsigned long long*)d_ws;
  _Float16* Khp = (_Float16*)((char*)d_ws + KHOFF);
  _Float16* Vhp = (_Float16*)((char*)d_ws + VHOFF);

  hipLaunchKernelGGL(prep_kernel, dim3(4096), dim3(256), 0, stream, M, K, V, Wb, Khp, Vhp);
  hipLaunchKernelGGL(fattn_kernel, dim3(B_ * H_ * (L_ / MBLK)), dim3(256), 0, stream,
                     Q, Khp, Vhp, Wb, O);
}